// Round 1
// baseline (458.180 us; speedup 1.0000x reference)
//
#include <hip/hip_runtime.h>
#include <hip/hip_bf16.h>

typedef unsigned short u16;
typedef unsigned int u32;
typedef __attribute__((ext_vector_type(8))) __bf16 bf16x8;
typedef __attribute__((ext_vector_type(4))) float f32x4;

#define GLD16(g, l) __builtin_amdgcn_global_load_lds((const __attribute__((address_space(1))) u32*)(g), (__attribute__((address_space(3))) u32*)(l), 16, 0, 0)

__device__ __forceinline__ u16 f2bf(float f) {
    u32 u = __float_as_uint(f);
    u += 0x7FFFu + ((u >> 16) & 1u);
    return (u16)(u >> 16);
}

__device__ __forceinline__ u32 flipf(float f) {
    u32 u = __float_as_uint(f);
    return (u >> 31) ? ~u : (u | 0x80000000u);
}

__device__ __forceinline__ float unflipf(u32 k) {
    return __uint_as_float((k >> 31) ? (k ^ 0x80000000u) : ~k);
}

// bilinear 14->28 taps (jax.image.resize, half-pixel, edge-renormalized)
__device__ __forceinline__ void taps(int o, int& i0, int& i1, float& w0, float& w1) {
    int k = (o - 1) >> 1;              // floor((o-1)/2)
    float fy = (0.5f * (float)o - 0.25f) - (float)k;
    i0 = k; i1 = k + 1;
    w0 = 1.0f - fy; w1 = fy;
    if (i0 < 0)  { i0 = 0;  w0 = 0.0f; w1 = 1.0f; }
    if (i1 > 13) { i1 = 13; w1 = 0.0f; w0 = 1.0f; }
}

// U[b,t,y,x] = 3x3 zero-padded box-sum of (feat3[b,2t] + feat3[b,2t+1]) on 14x14
__global__ __launch_bounds__(256) void u_kernel(const float* __restrict__ f3, float* __restrict__ U) {
    int idx = blockIdx.x * 256 + threadIdx.x;
    if (idx >= 8 * 512 * 196) return;
    int b = idx / (512 * 196);
    int rem = idx % (512 * 196);
    int t = rem / 196;
    int yx = rem % 196;
    int y = yx / 14, x = yx % 14;
    const float* p0 = f3 + ((size_t)(b * 1024 + 2 * t)) * 196;
    const float* p1 = p0 + 196;
    float s = 0.f;
    #pragma unroll
    for (int dy = -1; dy <= 1; ++dy) {
        int yy = y + dy; if ((unsigned)yy >= 14u) continue;
        #pragma unroll
        for (int dx = -1; dx <= 1; ++dx) {
            int xx = x + dx; if ((unsigned)xx >= 14u) continue;
            s += p0[yy * 14 + xx] + p1[yy * 14 + xx];
        }
    }
    U[idx] = s;
}

// memory bank: fp32 -> bf16 + row squared-norms (fp32)
__global__ __launch_bounds__(256) void mb_kernel(const float* __restrict__ mb, u16* __restrict__ mbb, float* __restrict__ mb2) {
    int m = blockIdx.x, tid = threadIdx.x;
    float4 v = ((const float4*)(mb + (size_t)m * 1024))[tid];
    ushort4 o;
    o.x = f2bf(v.x); o.y = f2bf(v.y); o.z = f2bf(v.z); o.w = f2bf(v.w);
    ((ushort4*)(mbb + (size_t)m * 1024))[tid] = o;
    float ssq = v.x * v.x + v.y * v.y + v.z * v.z + v.w * v.w;
    for (int s = 32; s; s >>= 1) ssq += __shfl_down(ssq, s);
    __shared__ float sm[4];
    if ((tid & 63) == 0) sm[tid >> 6] = ssq;
    __syncthreads();
    if (tid == 0) mb2[m] = sm[0] + sm[1] + sm[2] + sm[3];
}

// q[n, 0:512]  = weighted 3x3 mean of feat2 (center weight 2, /10)
// q[n, 512+t]  = bilinear(U[b,t])[h,w] / 18
// also qn2[n] = ||q_n||^2 (fp32), q stored bf16
__global__ __launch_bounds__(256) void q_kernel(const float* __restrict__ feat2, const float* __restrict__ U,
                                                u16* __restrict__ qb, float* __restrict__ qn2) {
    int n = blockIdx.x;
    int b = n / 784;
    int hw = n % 784;
    int h = hw / 28, w = hw % 28;
    int tid = threadIdx.x;
    int y0, y1, x0, x1; float wy0, wy1, wx0, wx1;
    taps(h, y0, y1, wy0, wy1);
    taps(w, x0, x1, wx0, wx1);
    float ssq = 0.f;
    #pragma unroll
    for (int k = 0; k < 4; ++k) {
        int d = tid + k * 256;
        float val;
        if (d < 512) {
            const float* p = feat2 + ((size_t)(b * 512 + d)) * 784;
            float s = 0.f;
            #pragma unroll
            for (int di = -1; di <= 1; ++di) {
                int y = h + di; if ((unsigned)y >= 28u) continue;
                #pragma unroll
                for (int dj = -1; dj <= 1; ++dj) {
                    int x = w + dj; if ((unsigned)x >= 28u) continue;
                    float v = p[y * 28 + x];
                    s += (di == 0 && dj == 0) ? 2.f * v : v;
                }
            }
            val = s * 0.1f;
        } else {
            const float* up = U + ((size_t)(b * 512 + (d - 512))) * 196;
            float v00 = up[y0 * 14 + x0], v01 = up[y0 * 14 + x1];
            float v10 = up[y1 * 14 + x0], v11 = up[y1 * 14 + x1];
            val = (wy0 * (wx0 * v00 + wx1 * v01) + wy1 * (wx0 * v10 + wx1 * v11)) * (1.f / 18.f);
        }
        ssq += val * val;
        qb[(size_t)n * 1024 + d] = f2bf(val);
    }
    for (int s = 32; s; s >>= 1) ssq += __shfl_down(ssq, s);
    __shared__ float sm[4];
    if ((tid & 63) == 0) sm[tid >> 6] = ssq;
    __syncthreads();
    if (tid == 0) qn2[n] = sm[0] + sm[1] + sm[2] + sm[3];
}

// 128x128x(K=1024) bf16 MFMA GEMM with fused min over memory dim.
// minkeys holds flip-encoded fp32 (atomicMin on u32 == float min).
__global__ __launch_bounds__(256) void gemm_min_kernel(
    const u16* __restrict__ qb, const u16* __restrict__ mbb,
    const float* __restrict__ qn2, const float* __restrict__ mb2,
    u32* __restrict__ minkeys) {
    __shared__ u16 As[128 * 32];
    __shared__ u16 Bs[128 * 32];
    __shared__ u32 rowmin[128];

    const int tid = threadIdx.x;
    const int wid = tid >> 6;
    const int lane = tid & 63;
    const int wm = wid >> 1, wn = wid & 1;
    const int n0 = blockIdx.x * 128;
    const int m0 = blockIdx.y * 128;
    const int scol = (lane & 3) * 8;

    f32x4 acc[4][4] = {};

    for (int kt = 0; kt < 32; ++kt) {
        const int k0 = kt * 32;
        #pragma unroll
        for (int i = 0; i < 2; ++i) {
            int r = wid * 32 + i * 16 + (lane >> 2);
            GLD16(qb + (size_t)(n0 + r) * 1024 + k0 + scol, &As[(wid * 32 + i * 16) * 32]);
            GLD16(mbb + (size_t)(m0 + r) * 1024 + k0 + scol, &Bs[(wid * 32 + i * 16) * 32]);
        }
        __syncthreads();
        bf16x8 a[4], bb[4];
        #pragma unroll
        for (int f = 0; f < 4; ++f) {
            a[f]  = *(const bf16x8*)&As[(wm * 64 + f * 16 + (lane & 15)) * 32 + (lane >> 4) * 8];
            bb[f] = *(const bf16x8*)&Bs[(wn * 64 + f * 16 + (lane & 15)) * 32 + (lane >> 4) * 8];
        }
        #pragma unroll
        for (int fi = 0; fi < 4; ++fi)
            #pragma unroll
            for (int fj = 0; fj < 4; ++fj)
                acc[fi][fj] = __builtin_amdgcn_mfma_f32_16x16x32_bf16(a[fi], bb[fj], acc[fi][fj], 0, 0, 0);
        __syncthreads();
    }

    if (tid < 128) rowmin[tid] = 0xFFFFFFFFu;
    __syncthreads();

    #pragma unroll
    for (int fi = 0; fi < 4; ++fi) {
        #pragma unroll
        for (int r = 0; r < 4; ++r) {
            const int qrow = wm * 64 + fi * 16 + (lane >> 4) * 4 + r;
            const float qq = qn2[n0 + qrow];
            float v = 3.4e38f;
            #pragma unroll
            for (int fj = 0; fj < 4; ++fj) {
                const int mcol = wn * 64 + fj * 16 + (lane & 15);
                float d2 = qq + mb2[m0 + mcol] - 2.0f * acc[fi][fj][r];
                v = fminf(v, d2);
            }
            #pragma unroll
            for (int s = 1; s < 16; s <<= 1) v = fminf(v, __shfl_xor(v, s));
            if ((lane & 15) == 0) atomicMin(&rowmin[qrow], flipf(v));
        }
    }
    __syncthreads();
    if (tid < 128) atomicMin(minkeys + n0 + tid, rowmin[tid]);
}

// per-image max + write patch scores
__global__ __launch_bounds__(256) void final_kernel(const u32* __restrict__ keys, float* __restrict__ out) {
    int b = blockIdx.x, tid = threadIdx.x;
    float mx = -3.4e38f;
    for (int i = tid; i < 784; i += 256) {
        float f = unflipf(keys[b * 784 + i]);
        out[8 + b * 784 + i] = f;
        mx = fmaxf(mx, f);
    }
    for (int s = 32; s; s >>= 1) mx = fmaxf(mx, __shfl_down(mx, s));
    __shared__ float sm[4];
    if ((tid & 63) == 0) sm[tid >> 6] = mx;
    __syncthreads();
    if (tid == 0) out[b] = fmaxf(fmaxf(sm[0], sm[1]), fmaxf(sm[2], sm[3]));
}

extern "C" void kernel_launch(void* const* d_in, const int* in_sizes, int n_in,
                              void* d_out, int out_size, void* d_ws, size_t ws_size,
                              hipStream_t stream) {
    const float* feat2 = (const float*)d_in[0];   // [8,512,28,28]
    const float* feat3 = (const float*)d_in[1];   // [8,1024,14,14]
    const float* mb    = (const float*)d_in[2];   // [16384,1024]
    float* out = (float*)d_out;                   // [8] image + [8,28,28] patch

    char* ws = (char*)d_ws;
    float* U      = (float*)(ws);                  // 3,211,264 B
    u16*   qb     = (u16*)  (ws + 3211264);        // 12,845,056 B
    u16*   mbb    = (u16*)  (ws + 16056320);       // 33,554,432 B
    float* qn2    = (float*)(ws + 49610752);       // 25,088 B
    float* mb2    = (float*)(ws + 49635840);       // 65,536 B
    u32*   minkey = (u32*)  (ws + 49701376);       // 25,088 B

    hipMemsetAsync(minkey, 0xFF, 6272 * 4, stream);
    u_kernel<<<3136, 256, 0, stream>>>(feat3, U);
    mb_kernel<<<16384, 256, 0, stream>>>(mb, mbb, mb2);
    q_kernel<<<6272, 256, 0, stream>>>(feat2, U, qb, qn2);
    gemm_min_kernel<<<dim3(49, 128), 256, 0, stream>>>(qb, mbb, qn2, mb2, minkey);
    final_kernel<<<8, 256, 0, stream>>>(minkey, out);
}

// Round 2
// 430.974 us; speedup vs baseline: 1.0631x; 1.0631x over previous
//
#include <hip/hip_runtime.h>
#include <hip/hip_bf16.h>

typedef unsigned short u16;
typedef unsigned int u32;
typedef __attribute__((ext_vector_type(8))) __bf16 bf16x8;
typedef __attribute__((ext_vector_type(4))) float f32x4;

#define GLD16(g, l) __builtin_amdgcn_global_load_lds((const __attribute__((address_space(1))) u32*)(g), (__attribute__((address_space(3))) u32*)(l), 16, 0, 0)

__device__ __forceinline__ u16 f2bf(float f) {
    u32 u = __float_as_uint(f);
    u += 0x7FFFu + ((u >> 16) & 1u);
    return (u16)(u >> 16);
}

__device__ __forceinline__ u32 flipf(float f) {
    u32 u = __float_as_uint(f);
    return (u >> 31) ? ~u : (u | 0x80000000u);
}

__device__ __forceinline__ float unflipf(u32 k) {
    return __uint_as_float((k >> 31) ? (k ^ 0x80000000u) : ~k);
}

// bilinear 14->28 taps (jax.image.resize, half-pixel, edge-renormalized)
__device__ __forceinline__ void taps(int o, int& i0, int& i1, float& w0, float& w1) {
    int k = (o - 1) >> 1;
    float fy = (0.5f * (float)o - 0.25f) - (float)k;
    i0 = k; i1 = k + 1;
    w0 = 1.0f - fy; w1 = fy;
    if (i0 < 0)  { i0 = 0;  w0 = 0.0f; w1 = 1.0f; }
    if (i1 > 13) { i1 = 13; w1 = 0.0f; w0 = 1.0f; }
}

// U[b,t,y,x] = 3x3 zero-padded box-sum of (feat3[b,2t] + feat3[b,2t+1]) on 14x14
__global__ __launch_bounds__(256) void u_kernel(const float* __restrict__ f3, float* __restrict__ U) {
    int idx = blockIdx.x * 256 + threadIdx.x;
    if (idx >= 8 * 512 * 196) return;
    int b = idx / (512 * 196);
    int rem = idx % (512 * 196);
    int t = rem / 196;
    int yx = rem % 196;
    int y = yx / 14, x = yx % 14;
    const float* p0 = f3 + ((size_t)(b * 1024 + 2 * t)) * 196;
    const float* p1 = p0 + 196;
    float s = 0.f;
    #pragma unroll
    for (int dy = -1; dy <= 1; ++dy) {
        int yy = y + dy; if ((unsigned)yy >= 14u) continue;
        #pragma unroll
        for (int dx = -1; dx <= 1; ++dx) {
            int xx = x + dx; if ((unsigned)xx >= 14u) continue;
            s += p0[yy * 14 + xx] + p1[yy * 14 + xx];
        }
    }
    U[idx] = s;
}

// memory bank: fp32 -> bf16 + row squared-norms (fp32)
__global__ __launch_bounds__(256) void mb_kernel(const float* __restrict__ mb, u16* __restrict__ mbb, float* __restrict__ mb2) {
    int m = blockIdx.x, tid = threadIdx.x;
    float4 v = ((const float4*)(mb + (size_t)m * 1024))[tid];
    ushort4 o;
    o.x = f2bf(v.x); o.y = f2bf(v.y); o.z = f2bf(v.z); o.w = f2bf(v.w);
    ((ushort4*)(mbb + (size_t)m * 1024))[tid] = o;
    float ssq = v.x * v.x + v.y * v.y + v.z * v.z + v.w * v.w;
    for (int s = 32; s; s >>= 1) ssq += __shfl_down(ssq, s);
    __shared__ float sm[4];
    if ((tid & 63) == 0) sm[tid >> 6] = ssq;
    __syncthreads();
    if (tid == 0) mb2[m] = sm[0] + sm[1] + sm[2] + sm[3];
}

// q[n, 0:512] = weighted 3x3 mean of feat2; q[n, 512+t] = bilinear(U)[h,w]/18
__global__ __launch_bounds__(256) void q_kernel(const float* __restrict__ feat2, const float* __restrict__ U,
                                                u16* __restrict__ qb, float* __restrict__ qn2) {
    int n = blockIdx.x;
    int b = n / 784;
    int hw = n % 784;
    int h = hw / 28, w = hw % 28;
    int tid = threadIdx.x;
    int y0, y1, x0, x1; float wy0, wy1, wx0, wx1;
    taps(h, y0, y1, wy0, wy1);
    taps(w, x0, x1, wx0, wx1);
    float ssq = 0.f;
    #pragma unroll
    for (int k = 0; k < 4; ++k) {
        int d = tid + k * 256;
        float val;
        if (d < 512) {
            const float* p = feat2 + ((size_t)(b * 512 + d)) * 784;
            float s = 0.f;
            #pragma unroll
            for (int di = -1; di <= 1; ++di) {
                int y = h + di; if ((unsigned)y >= 28u) continue;
                #pragma unroll
                for (int dj = -1; dj <= 1; ++dj) {
                    int x = w + dj; if ((unsigned)x >= 28u) continue;
                    float v = p[y * 28 + x];
                    s += (di == 0 && dj == 0) ? 2.f * v : v;
                }
            }
            val = s * 0.1f;
        } else {
            const float* up = U + ((size_t)(b * 512 + (d - 512))) * 196;
            float v00 = up[y0 * 14 + x0], v01 = up[y0 * 14 + x1];
            float v10 = up[y1 * 14 + x0], v11 = up[y1 * 14 + x1];
            val = (wy0 * (wx0 * v00 + wx1 * v01) + wy1 * (wx0 * v10 + wx1 * v11)) * (1.f / 18.f);
        }
        ssq += val * val;
        qb[(size_t)n * 1024 + d] = f2bf(val);
    }
    for (int s = 32; s; s >>= 1) ssq += __shfl_down(ssq, s);
    __shared__ float sm[4];
    if ((tid & 63) == 0) sm[tid >> 6] = ssq;
    __syncthreads();
    if (tid == 0) qn2[n] = sm[0] + sm[1] + sm[2] + sm[3];
}

// 256x256-tile BK=32 bf16 MFMA GEMM, 4-deep LDS pipeline, counted vmcnt,
// both-sides XOR swizzle, fused min over memory dim.
// M=6400 (padded q rows), N=16384, K=1024.
__global__ __launch_bounds__(512, 2) void gemm_min_kernel(
    const u16* __restrict__ qb, const u16* __restrict__ mbb,
    const float* __restrict__ qn2, const float* __restrict__ mb2,
    u32* __restrict__ minkeys) {
    __shared__ __align__(16) u16 As[4][8192];
    __shared__ __align__(16) u16 Bs[4][8192];
    __shared__ u32 rowmin[256];

    const int tid = threadIdx.x;
    const int wid = tid >> 6;
    const int lane = tid & 63;
    const int wm = wid >> 2;   // 2 M-waves
    const int wn = wid & 3;    // 4 N-waves

    // XCD-aware bijective swizzle: 1600 blocks, 8 XCDs, 200/XCD.
    const int flat = blockIdx.x;
    const int swz = (flat & 7) * 200 + (flat >> 3);
    const int q0 = (swz % 25) * 256;   // q-row (M) panel
    const int m0 = (swz / 25) * 256;   // memory-bank (N) panel

    // staging: per thread 2 A-loads + 2 B-loads per K-tile (16B each).
    // LDS dest is linear (wave-uniform base + lane*16); global source slot
    // is pre-swizzled with XOR (row>>1)&3 so swizzled reads see G[row][g].
    size_t gA[2], gB[2];
    u32 ldsOff[2];
    #pragma unroll
    for (int l = 0; l < 2; ++l) {
        int r = l * 128 + wid * 16 + (lane >> 2);
        int s = (lane & 3) ^ ((r >> 1) & 3);
        gA[l] = (size_t)(q0 + r) * 1024 + s * 8;
        gB[l] = (size_t)(m0 + r) * 1024 + s * 8;
        ldsOff[l] = l * 4096 + wid * 512;   // u16 elements, wave-uniform
    }

    // fragment read offsets (u16 elements), swizzled
    u32 offA[8], offB[4];
    #pragma unroll
    for (int m = 0; m < 8; ++m) {
        int r = wm * 128 + m * 16 + (lane & 15);
        offA[m] = r * 32 + (((lane >> 4) ^ ((r >> 1) & 3)) * 8);
    }
    #pragma unroll
    for (int n = 0; n < 4; ++n) {
        int r = wn * 64 + n * 16 + (lane & 15);
        offB[n] = r * 32 + (((lane >> 4) ^ ((r >> 1) & 3)) * 8);
    }

    #define STAGE_A(T) { const int _t = (T); \
        GLD16(qb + gA[0] + _t * 32, &As[_t & 3][ldsOff[0]]); \
        GLD16(qb + gA[1] + _t * 32, &As[_t & 3][ldsOff[1]]); }
    #define STAGE_B(T) { const int _t = (T); \
        GLD16(mbb + gB[0] + _t * 32, &Bs[_t & 3][ldsOff[0]]); \
        GLD16(mbb + gB[1] + _t * 32, &Bs[_t & 3][ldsOff[1]]); }

    // prologue: tiles 0,1,2 in flight; wait until tile 0 landed (8 left)
    STAGE_A(0); STAGE_B(0);
    STAGE_A(1); STAGE_B(1);
    STAGE_A(2); STAGE_B(2);
    asm volatile("s_waitcnt vmcnt(8)" ::: "memory");
    __builtin_amdgcn_s_barrier();
    __builtin_amdgcn_sched_barrier(0);

    f32x4 acc[8][4] = {};

    for (int t = 0; t < 32; ++t) {
        const u16* Ab = As[t & 3];
        const u16* Bb = Bs[t & 3];
        bf16x8 a[4], b[4];
        // ---- phase A: frags(mrows 0-63) + B frags; stage A of tile t+3
        #pragma unroll
        for (int n = 0; n < 4; ++n) b[n] = *(const bf16x8*)&Bb[offB[n]];
        #pragma unroll
        for (int m = 0; m < 4; ++m) a[m] = *(const bf16x8*)&Ab[offA[m]];
        if (t < 29) STAGE_A(t + 3);
        __builtin_amdgcn_s_barrier();
        __builtin_amdgcn_sched_barrier(0);
        __builtin_amdgcn_s_setprio(1);
        #pragma unroll
        for (int m = 0; m < 4; ++m)
            #pragma unroll
            for (int n = 0; n < 4; ++n)
                acc[m][n] = __builtin_amdgcn_mfma_f32_16x16x32_bf16(a[m], b[n], acc[m][n], 0, 0, 0);
        __builtin_amdgcn_s_setprio(0);
        __builtin_amdgcn_s_barrier();
        __builtin_amdgcn_sched_barrier(0);
        // ---- phase B: frags(mrows 64-127), B reused from regs; stage B of t+3
        #pragma unroll
        for (int m = 0; m < 4; ++m) a[m] = *(const bf16x8*)&Ab[offA[4 + m]];
        if (t < 29) STAGE_B(t + 3);
        __builtin_amdgcn_s_barrier();
        __builtin_amdgcn_sched_barrier(0);
        __builtin_amdgcn_s_setprio(1);
        #pragma unroll
        for (int m = 0; m < 4; ++m)
            #pragma unroll
            for (int n = 0; n < 4; ++n)
                acc[4 + m][n] = __builtin_amdgcn_mfma_f32_16x16x32_bf16(a[m], b[n], acc[4 + m][n], 0, 0, 0);
        __builtin_amdgcn_s_setprio(0);
        // ---- end of tile: counted vmcnt (tile t+1 fully landed), publish
        if (t < 29)       { asm volatile("s_waitcnt vmcnt(8)" ::: "memory"); }
        else if (t == 29) { asm volatile("s_waitcnt vmcnt(4)" ::: "memory"); }
        else              { asm volatile("s_waitcnt vmcnt(0)" ::: "memory"); }
        __builtin_amdgcn_s_barrier();
        __builtin_amdgcn_sched_barrier(0);
    }

    // ---- epilogue: fused min over memory dim
    if (tid < 256) rowmin[tid] = 0xFFFFFFFFu;
    __syncthreads();

    float mb2v[4];
    #pragma unroll
    for (int n = 0; n < 4; ++n) mb2v[n] = mb2[m0 + wn * 64 + n * 16 + (lane & 15)];

    #pragma unroll
    for (int m = 0; m < 8; ++m) {
        #pragma unroll
        for (int r = 0; r < 4; ++r) {
            const int qrow = wm * 128 + m * 16 + (lane >> 4) * 4 + r;
            const float qq = qn2[q0 + qrow];
            float v = 3.4e38f;
            #pragma unroll
            for (int n = 0; n < 4; ++n) {
                float d2 = qq + mb2v[n] - 2.0f * acc[m][n][r];
                v = fminf(v, d2);
            }
            #pragma unroll
            for (int s = 1; s < 16; s <<= 1) v = fminf(v, __shfl_xor(v, s));
            if ((lane & 15) == 0) atomicMin(&rowmin[qrow], flipf(v));
        }
    }
    __syncthreads();
    if (tid < 256) atomicMin(minkeys + q0 + tid, rowmin[tid]);
}

// per-image max + write patch scores
__global__ __launch_bounds__(256) void final_kernel(const u32* __restrict__ keys, float* __restrict__ out) {
    int b = blockIdx.x, tid = threadIdx.x;
    float mx = -3.4e38f;
    for (int i = tid; i < 784; i += 256) {
        float f = unflipf(keys[b * 784 + i]);
        out[8 + b * 784 + i] = f;
        mx = fmaxf(mx, f);
    }
    for (int s = 32; s; s >>= 1) mx = fmaxf(mx, __shfl_down(mx, s));
    __shared__ float sm[4];
    if ((tid & 63) == 0) sm[tid >> 6] = mx;
    __syncthreads();
    if (tid == 0) out[b] = fmaxf(fmaxf(sm[0], sm[1]), fmaxf(sm[2], sm[3]));
}

extern "C" void kernel_launch(void* const* d_in, const int* in_sizes, int n_in,
                              void* d_out, int out_size, void* d_ws, size_t ws_size,
                              hipStream_t stream) {
    const float* feat2 = (const float*)d_in[0];   // [8,512,28,28]
    const float* feat3 = (const float*)d_in[1];   // [8,1024,14,14]
    const float* mb    = (const float*)d_in[2];   // [16384,1024]
    float* out = (float*)d_out;                   // [8] image + [8,28,28] patch

    char* ws = (char*)d_ws;
    float* U      = (float*)(ws);                  // 3,211,264 B
    u16*   qb     = (u16*)  (ws + 3211264);        // 6400*1024*2 = 13,107,200 B
    u16*   mbb    = (u16*)  (ws + 16318464);       // 33,554,432 B
    float* qn2    = (float*)(ws + 49872896);       // 25,088 B
    float* mb2    = (float*)(ws + 49897984);       // 65,536 B
    u32*   minkey = (u32*)  (ws + 49963520);       // 25,600 B

    hipMemsetAsync(minkey, 0xFF, 6400 * 4, stream);
    hipMemsetAsync(qb + (size_t)6272 * 1024, 0, (size_t)128 * 1024 * 2, stream);  // zero pad rows
    u_kernel<<<3136, 256, 0, stream>>>(feat3, U);
    mb_kernel<<<16384, 256, 0, stream>>>(mb, mbb, mb2);
    q_kernel<<<6272, 256, 0, stream>>>(feat2, U, qb, qn2);
    gemm_min_kernel<<<1600, 512, 0, stream>>>(qb, mbb, qn2, mb2, minkey);
    final_kernel<<<8, 256, 0, stream>>>(minkey, out);
}